// Round 3
// baseline (270.257 us; speedup 1.0000x reference)
//
#include <hip/hip_runtime.h>

#define DIM_ 768
#define MID_ 96

typedef float f32x4 __attribute__((ext_vector_type(4)));
typedef __bf16 bf16x8 __attribute__((ext_vector_type(8)));
typedef __bf16 bf16x4 __attribute__((ext_vector_type(4)));

// ---------------------------------------------------------------------------
// K_wprep: fp32->bf16 casts for up_w, pw_w + zero gvec partials.
// ---------------------------------------------------------------------------
__global__ __launch_bounds__(256) void k_wprep(const float* __restrict__ uw,
        const float* __restrict__ pw, __bf16* __restrict__ bup,
        __bf16* __restrict__ bpw, float* __restrict__ part) {
    const int t = blockIdx.x * 256 + threadIdx.x;
    const float* src;
    __bf16* dst;
    int i;
    if (t < 18432)      { src = uw; dst = bup; i = t; }
    else if (t < 23040) { src = pw; dst = bpw; i = t - 18432; }
    else if (t < 23808) { part[t - 23040] = 0.f; return; }
    else return;
    float4 v = reinterpret_cast<const float4*>(src)[i];
    bf16x4 o;
    o[0] = (__bf16)v.x; o[1] = (__bf16)v.y; o[2] = (__bf16)v.z; o[3] = (__bf16)v.w;
    *reinterpret_cast<bf16x4*>(dst + (size_t)i * 4) = o;
}

// ---------------------------------------------------------------------------
// K_wfold: fold LN scale into down weights.
// Wln[n,k] = W[n,k]*lnw[k] (bf16);  sw[n] = sum_k bf16(Wln[n,k]);
// cb[n] = sum_k lnb[k]*W[n,k] + bias[n].
// 192 waves: wave -> (mat, n).
// ---------------------------------------------------------------------------
__global__ __launch_bounds__(256) void k_wfold(
        const float* __restrict__ dw, const float* __restrict__ db,
        const float* __restrict__ lnw0, const float* __restrict__ lnb0,
        const float* __restrict__ d1w, const float* __restrict__ d1b,
        const float* __restrict__ lnw1, const float* __restrict__ lnb1,
        __bf16* __restrict__ wln0, __bf16* __restrict__ wln1,
        float* __restrict__ swcb) {
    const int wid = blockIdx.x * 4 + (threadIdx.x >> 6);
    const int lane = threadIdx.x & 63;
    const int mat = wid >= 96;
    const int n = mat ? wid - 96 : wid;
    const float* W   = mat ? d1w : dw;
    const float* bia = mat ? d1b : db;
    const float* lw  = mat ? lnw1 : lnw0;
    const float* lb  = mat ? lnb1 : lnb0;
    __bf16* dst = mat ? wln1 : wln0;
    float sacc = 0.f, cacc = 0.f;
#pragma unroll
    for (int j = 0; j < 12; ++j) {
        const int k = j * 64 + lane;
        const float w = W[(size_t)n * DIM_ + k];
        const float val = w * lw[k];
        const __bf16 bv = (__bf16)val;
        dst[(size_t)n * DIM_ + k] = bv;
        sacc += (float)bv;
        cacc += lb[k] * w;
    }
#pragma unroll
    for (int m = 1; m < 64; m <<= 1) {
        sacc += __shfl_xor(sacc, m, 64);
        cacc += __shfl_xor(cacc, m, 64);
    }
    if (lane == 0) {
        // layout: sw0[96] cb0[96] sw1[96] cb1[96]
        swcb[mat * 192 + n] = sacc;
        swcb[mat * 192 + 96 + n] = cacc + bia[n];
    }
}

// ---------------------------------------------------------------------------
// K_downf: single-pass fused LN+GEMM via weight folding.
// Stage raw x tile as bf16 in LDS (computing row sums on the fly), then
// barrier-free GEMM with B from L2; epilogue applies rstd / mu*rstd / cb.
// Block: 256 thr, 32 rows; wave (w&1)->rows, (w>>1)->48-col half.
// ---------------------------------------------------------------------------
__global__ __launch_bounds__(256) void k_downf(const float* __restrict__ src,
        const __bf16* __restrict__ wln, const float* __restrict__ swcb,
        __bf16* __restrict__ outb, float* __restrict__ part) {
    __shared__ bf16x8 As[32][97];   // row stride 1552 B: R%32w = 4 -> 2-way max
    __shared__ float st[32][2];     // {rstd, mu*rstd}
    const int t = threadIdx.x;
    const int row0 = blockIdx.x * 32;
    const int r = t >> 3, c8 = t & 7;
    const float* rp = src + (size_t)(row0 + r) * DIM_;
    __bf16* arow = (__bf16*)&As[r][0];

    float s = 0.f, sq = 0.f;
#pragma unroll
    for (int j = 0; j < 24; ++j) {
        const int slot = c8 + j * 8;                 // float4 slot in row
        float4 v = *reinterpret_cast<const float4*>(rp + slot * 4);
        s += v.x + v.y + v.z + v.w;
        sq += v.x * v.x + v.y * v.y + v.z * v.z + v.w * v.w;
        bf16x4 o;
        o[0] = (__bf16)v.x; o[1] = (__bf16)v.y;
        o[2] = (__bf16)v.z; o[3] = (__bf16)v.w;
        *reinterpret_cast<bf16x4*>(arow + slot * 4) = o;
    }
    s += __shfl_xor(s, 1, 64); sq += __shfl_xor(sq, 1, 64);
    s += __shfl_xor(s, 2, 64); sq += __shfl_xor(sq, 2, 64);
    s += __shfl_xor(s, 4, 64); sq += __shfl_xor(sq, 4, 64);
    if (c8 == 0) {
        const float mean = s * (1.f / 768.f);
        const float rstd = rsqrtf(sq * (1.f / 768.f) - mean * mean + 1e-6f);
        st[r][0] = rstd;
        st[r][1] = mean * rstd;
    }
    __syncthreads();

    const int lane = t & 63, wave = t >> 6;
    const int l15 = lane & 15, l4 = lane >> 4;
    const int mrow = (wave & 1) * 16;
    const int ncol = (wave >> 1) * 48;
    f32x4 acc[3] = {};
    const __bf16* b0 = wln + (size_t)(ncol + l15) * DIM_ + l4 * 8;
#pragma unroll
    for (int kt = 0; kt < 24; ++kt) {
        bf16x8 a = As[mrow + l15][kt * 4 + l4];
#pragma unroll
        for (int f = 0; f < 3; ++f) {
            bf16x8 b = *reinterpret_cast<const bf16x8*>(
                b0 + (size_t)f * 16 * DIM_ + kt * 32);
            acc[f] = __builtin_amdgcn_mfma_f32_16x16x32_bf16(a, b, acc[f], 0, 0, 0);
        }
    }

    const int batch = blockIdx.x >> 7;   // 128 blocks per batch image
#pragma unroll
    for (int f = 0; f < 3; ++f) {
        const int col = ncol + f * 16 + l15;
        const float swc = swcb[col];
        const float cbc = swcb[96 + col];
        float colsum = 0.f;
#pragma unroll
        for (int rr = 0; rr < 4; ++rr) {
            const int lrow = mrow + l4 * 4 + rr;
            const float val = acc[f][rr] * st[lrow][0] - st[lrow][1] * swc + cbc;
            outb[(size_t)(row0 + lrow) * MID_ + col] = (__bf16)val;
            colsum += val;
        }
        if (part) {
            colsum += __shfl_xor(colsum, 16, 64);
            colsum += __shfl_xor(colsum, 32, 64);
            if (l4 == 0) atomicAdd(&part[batch * MID_ + col], colsum);
        }
    }
}

// ---------------------------------------------------------------------------
// K_mlp: gvec mean from part, MLP (96->24 relu ->4), softmax -> wts [8,4]
// ---------------------------------------------------------------------------
__global__ __launch_bounds__(128) void k_mlp(const float* __restrict__ part,
        const float* __restrict__ m1w, const float* __restrict__ m1b,
        const float* __restrict__ m2w, const float* __restrict__ m2b,
        float* __restrict__ wts) {
    const int b = blockIdx.x, t = threadIdx.x;
    __shared__ float gv[96];
    __shared__ float hid[24];
    __shared__ float lg[4];
    if (t < 96) gv[t] = part[b * MID_ + t] * (1.f / 4096.f);
    __syncthreads();
    if (t < 24) {
        float s = m1b[t];
        for (int c = 0; c < 96; ++c) s += gv[c] * m1w[t * 96 + c];
        hid[t] = fmaxf(s, 0.f);
    }
    __syncthreads();
    if (t < 4) {
        float s = m2b[t];
        for (int j = 0; j < 24; ++j) s += hid[j] * m2w[t * 24 + j];
        lg[t] = s;
    }
    __syncthreads();
    if (t < 4) {
        const float m = fmaxf(fmaxf(lg[0], lg[1]), fmaxf(lg[2], lg[3]));
        const float e = __expf(lg[t] - m);
        const float sum = __expf(lg[0] - m) + __expf(lg[1] - m) +
                          __expf(lg[2] - m) + __expf(lg[3] - m);
        wts[b * 4 + t] = e / sum;
    }
}

// ---------------------------------------------------------------------------
// K_dwconv: depthwise 3x3 conv (zero pad) + SiLU. temb bf16 -> y bf16.
// ---------------------------------------------------------------------------
__global__ __launch_bounds__(256) void k_dwconv(const __bf16* __restrict__ temb,
        const float* __restrict__ dww, const float* __restrict__ dwb,
        __bf16* __restrict__ y) {
    __shared__ float wls[96 * 9];
    __shared__ float bls[96];
    const int t = threadIdx.x;
    for (int i = t; i < 96 * 9; i += 256) wls[i] = dww[i];
    if (t < 96) bls[t] = dwb[t];
    __syncthreads();
    const int b = blockIdx.x >> 6, h = blockIdx.x & 63;
    const __bf16* base = temb + (size_t)b * 4096 * MID_;
    for (int o = t; o < 64 * 96; o += 256) {
        const int w = o / 96;
        const int c = o - w * 96;
        float acc = bls[c];
#pragma unroll
        for (int dh = 0; dh < 3; ++dh) {
            const int hh = h + dh - 1;
            if (hh < 0 || hh > 63) continue;
#pragma unroll
            for (int dw = 0; dw < 3; ++dw) {
                const int ww = w + dw - 1;
                if (ww < 0 || ww > 63) continue;
                acc += (float)base[((size_t)hh * 64 + ww) * MID_ + c] *
                       wls[c * 9 + dh * 3 + dw];
            }
        }
        y[((size_t)(b * 64 + h) * 64 + w) * MID_ + c] =
            (__bf16)(acc / (1.f + __expf(-acc)));
    }
}

// ---------------------------------------------------------------------------
// K_style: style GEMM (y @ pw_w^T + pw_b) fused with modulation:
// common = x_emb * (1 + gamma) + beta -> bf16. K=96 fully staged, 1 barrier.
// ---------------------------------------------------------------------------
__global__ __launch_bounds__(256) void k_style(const __bf16* __restrict__ y,
        const __bf16* __restrict__ wpw, const float* __restrict__ pwb,
        const __bf16* __restrict__ xemb, __bf16* __restrict__ common) {
    __shared__ bf16x8 As[64][13];
    __shared__ bf16x8 Bs[192][13];
    const int t = threadIdx.x;
    const int row0 = blockIdx.x * 64;
    for (int idx = t; idx < 768; idx += 256) {
        const int rr = idx / 12, q = idx - rr * 12;
        As[rr][q] = *reinterpret_cast<const bf16x8*>(
            y + (size_t)(row0 + rr) * MID_ + q * 8);
    }
    for (int idx = t; idx < 2304; idx += 256) {
        const int rr = idx / 12, q = idx - rr * 12;
        Bs[rr][q] = *reinterpret_cast<const bf16x8*>(
            wpw + (size_t)rr * MID_ + q * 8);
    }
    __syncthreads();
    const int lane = t & 63, wave = t >> 6;
    const int l15 = lane & 15, l4 = lane >> 4;
    f32x4 acc[12] = {};
    const int ar = wave * 16 + l15;
#pragma unroll
    for (int kt = 0; kt < 3; ++kt) {
        bf16x8 a = As[ar][kt * 4 + l4];
#pragma unroll
        for (int f = 0; f < 12; ++f) {
            bf16x8 b = Bs[f * 16 + l15][kt * 4 + l4];
            acc[f] = __builtin_amdgcn_mfma_f32_16x16x32_bf16(a, b, acc[f], 0, 0, 0);
        }
    }
    const int orow = row0 + wave * 16 + l4 * 4;
#pragma unroll
    for (int f = 0; f < 6; ++f) {
        const int col = f * 16 + l15;
        const float pbg = pwb[col];
        const float pbb = pwb[col + 96];
#pragma unroll
        for (int rr = 0; rr < 4; ++rr) {
            const float g = acc[f][rr] + pbg;
            const float bt = acc[f + 6][rr] + pbb;
            const float xe = (float)xemb[(size_t)(orow + rr) * MID_ + col];
            common[(size_t)(orow + rr) * MID_ + col] = (__bf16)(xe * (1.f + g) + bt);
        }
    }
}

// ---------------------------------------------------------------------------
// K_circ: circular 7x7 conv (== rfft2/irfft2 product). dyn built in LDS.
// ---------------------------------------------------------------------------
__global__ __launch_bounds__(192) void k_circ(const __bf16* __restrict__ common,
        const float* __restrict__ wts, const float* __restrict__ basis,
        __bf16* __restrict__ outc) {
    __shared__ float dyn[49][96];
    const int t = threadIdx.x;
    const int b = blockIdx.x >> 7;
    const int h = (blockIdx.x >> 1) & 63;
    const int wslice = blockIdx.x & 1;
    const float w0 = wts[b * 4 + 0], w1 = wts[b * 4 + 1];
    const float w2 = wts[b * 4 + 2], w3 = wts[b * 4 + 3];
    for (int idx = t; idx < 4704; idx += 192) {
        const int c = idx / 49;
        const int pq = idx - c * 49;
        const size_t off = (size_t)c * 49 + pq;
        dyn[pq][c] = w0 * basis[off] + w1 * basis[off + 4704] +
                     w2 * basis[off + 9408] + w3 * basis[off + 14112];
    }
    __syncthreads();
    const int c = t % 96;
    const int wg = t / 96;
    const int wbase = wslice * 32 + wg * 16;
    const __bf16* cb = common + (size_t)b * 4096 * MID_ + c;
    float acc[16] = {};
#pragma unroll 1
    for (int p = 0; p < 7; ++p) {
        const int hh = (h + 3 - p) & 63;
        const __bf16* rp = cb + (size_t)hh * 64 * MID_;
        float dynr[7];
#pragma unroll
        for (int q = 0; q < 7; ++q) dynr[q] = dyn[p * 7 + q][c];
#pragma unroll
        for (int i = 0; i < 22; ++i) {
            const int ww = (wbase - 3 + i) & 63;
            const float cm = (float)rp[(size_t)ww * MID_];
#pragma unroll
            for (int q = 0; q < 7; ++q) {
                const int li = i + q - 6;
                if (li >= 0 && li < 16) acc[li] += dynr[q] * cm;
            }
        }
    }
    const size_t obase = ((size_t)(b * 64 + h) * 64 + wbase) * MID_ + c;
#pragma unroll
    for (int li = 0; li < 16; ++li)
        outc[obase + (size_t)li * MID_] = (__bf16)acc[li];
}

// ---------------------------------------------------------------------------
// K_up: out = a_in[32768,96] @ up_w_bf16[768,96]^T + up_b + x  (fp32 out)
// ---------------------------------------------------------------------------
__global__ __launch_bounds__(256) void k_up(const __bf16* __restrict__ a_in,
        const __bf16* __restrict__ wbf, const float* __restrict__ upb,
        const float* __restrict__ x, float* __restrict__ out) {
    __shared__ bf16x8 As[128][13];
    __shared__ bf16x8 Ws[96][13];
    const int t = threadIdx.x;
    const int mt = blockIdx.x >> 3, nt = blockIdx.x & 7;
    const int row0 = mt * 128, col0 = nt * 96;
    for (int idx = t; idx < 1536; idx += 256) {
        const int rr = idx / 12, q = idx - rr * 12;
        As[rr][q] = *reinterpret_cast<const bf16x8*>(
            a_in + (size_t)(row0 + rr) * MID_ + q * 8);
    }
    for (int idx = t; idx < 1152; idx += 256) {
        const int rr = idx / 12, q = idx - rr * 12;
        Ws[rr][q] = *reinterpret_cast<const bf16x8*>(
            wbf + (size_t)(col0 + rr) * MID_ + q * 8);
    }
    __syncthreads();
    const int lane = t & 63, wave = t >> 6;
    const int l15 = lane & 15, l4 = lane >> 4;
    f32x4 acc[2][6] = {};
#pragma unroll
    for (int kt = 0; kt < 3; ++kt) {
        bf16x8 a0 = As[wave * 32 + l15][kt * 4 + l4];
        bf16x8 a1 = As[wave * 32 + 16 + l15][kt * 4 + l4];
#pragma unroll
        for (int f = 0; f < 6; ++f) {
            bf16x8 b = Ws[f * 16 + l15][kt * 4 + l4];
            acc[0][f] = __builtin_amdgcn_mfma_f32_16x16x32_bf16(a0, b, acc[0][f], 0, 0, 0);
            acc[1][f] = __builtin_amdgcn_mfma_f32_16x16x32_bf16(a1, b, acc[1][f], 0, 0, 0);
        }
    }
#pragma unroll
    for (int mr = 0; mr < 2; ++mr) {
        const int orow = row0 + wave * 32 + mr * 16 + l4 * 4;
#pragma unroll
        for (int f = 0; f < 6; ++f) {
            const int col = col0 + f * 16 + l15;
            const float ub = upb[col];
#pragma unroll
            for (int rr = 0; rr < 4; ++rr) {
                const size_t idx = (size_t)(orow + rr) * DIM_ + col;
                out[idx] = acc[mr][f][rr] + ub + x[idx];
            }
        }
    }
}

// ---------------------------------------------------------------------------
extern "C" void kernel_launch(void* const* d_in, const int* in_sizes, int n_in,
                              void* d_out, int out_size, void* d_ws, size_t ws_size,
                              hipStream_t stream) {
    (void)in_sizes; (void)n_in; (void)out_size; (void)ws_size;
    const float* x      = (const float*)d_in[0];
    const float* tt     = (const float*)d_in[1];
    const float* ln_w   = (const float*)d_in[2];
    const float* ln_b   = (const float*)d_in[3];
    const float* down_w = (const float*)d_in[4];
    const float* down_b = (const float*)d_in[5];
    const float* ln1_w  = (const float*)d_in[6];
    const float* ln1_b  = (const float*)d_in[7];
    const float* down1_w= (const float*)d_in[8];
    const float* down1_b= (const float*)d_in[9];
    const float* dw_w   = (const float*)d_in[10];
    const float* dw_b   = (const float*)d_in[11];
    const float* pw_w   = (const float*)d_in[12];
    const float* pw_b   = (const float*)d_in[13];
    const float* m1w    = (const float*)d_in[14];
    const float* m1b    = (const float*)d_in[15];
    const float* m2w    = (const float*)d_in[16];
    const float* m2b    = (const float*)d_in[17];
    const float* basis  = (const float*)d_in[18];
    const float* up_w   = (const float*)d_in[19];
    const float* up_b   = (const float*)d_in[20];
    float* out = (float*)d_out;
    char* ws = (char*)d_ws;

    // workspace layout (bytes)
    __bf16* wln_down  = (__bf16*)(ws + 0);          // 96*768*2  = 147456
    __bf16* wln_down1 = (__bf16*)(ws + 147456);
    __bf16* wbf_up    = (__bf16*)(ws + 294912);     // 768*96*2
    __bf16* wbf_pw    = (__bf16*)(ws + 442368);     // 192*96*2 = 36864
    float*  part      = (float*)(ws + 479232);      // 8*96*4 = 3072
    float*  wts       = (float*)(ws + 482304);      // 32*4
    float*  swcb      = (float*)(ws + 482560);      // 2*192*4 = 1536
    __bf16* x_emb     = (__bf16*)(ws + 524288);     // 32768*96*2 = 6291456
    __bf16* t_emb     = (__bf16*)(ws + 6815744);
    __bf16* ybuf      = (__bf16*)(ws + 13107200);
    __bf16* common    = (__bf16*)(ws + 19398656);
    __bf16* convout   = (__bf16*)(ws + 25690112);

    k_wprep<<<93, 256, 0, stream>>>(up_w, pw_w, wbf_up, wbf_pw, part);
    k_wfold<<<48, 256, 0, stream>>>(down_w, down_b, ln_w, ln_b,
                                    down1_w, down1_b, ln1_w, ln1_b,
                                    wln_down, wln_down1, swcb);
    k_downf<<<1024, 256, 0, stream>>>(x, wln_down, swcb, x_emb, part);
    k_downf<<<1024, 256, 0, stream>>>(tt, wln_down1, swcb + 192, t_emb, nullptr);
    k_mlp<<<8, 128, 0, stream>>>(part, m1w, m1b, m2w, m2b, wts);
    k_dwconv<<<512, 256, 0, stream>>>(t_emb, dw_w, dw_b, ybuf);
    k_style<<<512, 256, 0, stream>>>(ybuf, wbf_pw, pw_b, x_emb, common);
    k_circ<<<1024, 192, 0, stream>>>(common, wts, basis, convout);
    k_up<<<2048, 256, 0, stream>>>(convout, wbf_up, up_b, x, out);
}

// Round 4
// 203.286 us; speedup vs baseline: 1.3294x; 1.3294x over previous
//
#include <hip/hip_runtime.h>

#define DIM_ 768
#define MID_ 96

typedef float f32x4 __attribute__((ext_vector_type(4)));
typedef __bf16 bf16x8 __attribute__((ext_vector_type(8)));
typedef __bf16 bf16x4 __attribute__((ext_vector_type(4)));

// ---------------------------------------------------------------------------
// K_wprep: fp32->bf16 casts for up_w, pw_w + zero gvec partials.
// ---------------------------------------------------------------------------
__global__ __launch_bounds__(256) void k_wprep(const float* __restrict__ uw,
        const float* __restrict__ pw, __bf16* __restrict__ bup,
        __bf16* __restrict__ bpw, float* __restrict__ part) {
    const int t = blockIdx.x * 256 + threadIdx.x;
    const float* src;
    __bf16* dst;
    int i;
    if (t < 18432)      { src = uw; dst = bup; i = t; }
    else if (t < 23040) { src = pw; dst = bpw; i = t - 18432; }
    else if (t < 23808) { part[t - 23040] = 0.f; return; }
    else return;
    float4 v = reinterpret_cast<const float4*>(src)[i];
    bf16x4 o;
    o[0] = (__bf16)v.x; o[1] = (__bf16)v.y; o[2] = (__bf16)v.z; o[3] = (__bf16)v.w;
    *reinterpret_cast<bf16x4*>(dst + (size_t)i * 4) = o;
}

// ---------------------------------------------------------------------------
// K_wfold: fold LN scale into down weights.
// Wln[n,k] = W[n,k]*lnw[k] (bf16);  sw[n] = sum_k bf16(Wln[n,k]);
// cb[n] = sum_k lnb[k]*W[n,k] + bias[n].
// ---------------------------------------------------------------------------
__global__ __launch_bounds__(256) void k_wfold(
        const float* __restrict__ dw, const float* __restrict__ db,
        const float* __restrict__ lnw0, const float* __restrict__ lnb0,
        const float* __restrict__ d1w, const float* __restrict__ d1b,
        const float* __restrict__ lnw1, const float* __restrict__ lnb1,
        __bf16* __restrict__ wln0, __bf16* __restrict__ wln1,
        float* __restrict__ swcb) {
    const int wid = blockIdx.x * 4 + (threadIdx.x >> 6);
    const int lane = threadIdx.x & 63;
    const int mat = wid >= 96;
    const int n = mat ? wid - 96 : wid;
    const float* W   = mat ? d1w : dw;
    const float* bia = mat ? d1b : db;
    const float* lw  = mat ? lnw1 : lnw0;
    const float* lb  = mat ? lnb1 : lnb0;
    __bf16* dst = mat ? wln1 : wln0;
    float sacc = 0.f, cacc = 0.f;
#pragma unroll
    for (int j = 0; j < 12; ++j) {
        const int k = j * 64 + lane;
        const float w = W[(size_t)n * DIM_ + k];
        const float val = w * lw[k];
        const __bf16 bv = (__bf16)val;
        dst[(size_t)n * DIM_ + k] = bv;
        sacc += (float)bv;
        cacc += lb[k] * w;
    }
#pragma unroll
    for (int m = 1; m < 64; m <<= 1) {
        sacc += __shfl_xor(sacc, m, 64);
        cacc += __shfl_xor(cacc, m, 64);
    }
    if (lane == 0) {
        swcb[mat * 192 + n] = sacc;              // sw
        swcb[mat * 192 + 96 + n] = cacc + bia[n];// cb
    }
}

// ---------------------------------------------------------------------------
// K_downf: single-pass fused LN+GEMM, W fully LDS-resident in fragment order.
// Block: 512 thr (8 waves), 128 rows; grid 256 (1 block/CU).
// LDS layout: Wp[(kt*6 + f)*64 + lane][8] bf16 -> lane-contiguous ds_read_b128
// (zero bank conflicts). Main loop: независ. A-loads + 6 MFMA, no barriers.
// LN handled algebraically: acc*rstd - mu*rstd*sw + cb in epilogue; stats
// accumulated in-register during the A-load stream.
// ---------------------------------------------------------------------------
__global__ __launch_bounds__(512, 2) void k_downf(const float* __restrict__ src,
        const __bf16* __restrict__ wln, const float* __restrict__ swcb,
        __bf16* __restrict__ outb, float* __restrict__ part) {
    extern __shared__ __bf16 Wp[];   // 96*768 = 73728 elems = 147456 B
    const int t = threadIdx.x;
    // stage W in fragment order: idx = (kt*6 + f)*64 + lane
#pragma unroll
    for (int i = 0; i < 18; ++i) {
        const int idx = t + i * 512;           // 0..9215
        const int ls = idx & 63;
        const int rem = idx >> 6;              // kt*6 + f
        const int kt = rem / 6;
        const int f = rem - kt * 6;
        const int row = f * 16 + (ls & 15);
        const int col = kt * 32 + (ls >> 4) * 8;
        *reinterpret_cast<bf16x8*>(Wp + (size_t)idx * 8) =
            *reinterpret_cast<const bf16x8*>(wln + (size_t)row * DIM_ + col);
    }
    __syncthreads();

    const int lane = t & 63, wave = t >> 6;
    const int l15 = lane & 15, l4 = lane >> 4;
    const int row = blockIdx.x * 128 + wave * 16 + l15;
    const float* rp = src + (size_t)row * DIM_ + l4 * 8;

    float s = 0.f, sq = 0.f;
    f32x4 acc[6] = {};
#pragma unroll
    for (int kt = 0; kt < 24; ++kt) {
        float4 v0 = *reinterpret_cast<const float4*>(rp + kt * 32);
        float4 v1 = *reinterpret_cast<const float4*>(rp + kt * 32 + 4);
        s += v0.x + v0.y + v0.z + v0.w + v1.x + v1.y + v1.z + v1.w;
        sq += v0.x * v0.x + v0.y * v0.y + v0.z * v0.z + v0.w * v0.w +
              v1.x * v1.x + v1.y * v1.y + v1.z * v1.z + v1.w * v1.w;
        bf16x8 a;
        a[0] = (__bf16)v0.x; a[1] = (__bf16)v0.y;
        a[2] = (__bf16)v0.z; a[3] = (__bf16)v0.w;
        a[4] = (__bf16)v1.x; a[5] = (__bf16)v1.y;
        a[6] = (__bf16)v1.z; a[7] = (__bf16)v1.w;
        const __bf16* bp = Wp + ((size_t)kt * 6 * 64 + lane) * 8;
#pragma unroll
        for (int f = 0; f < 6; ++f) {
            bf16x8 b = *reinterpret_cast<const bf16x8*>(bp + (size_t)f * 64 * 8);
            acc[f] = __builtin_amdgcn_mfma_f32_16x16x32_bf16(a, b, acc[f], 0, 0, 0);
        }
    }
    // finish stats: combine the 4 k-quarter lanes of each row
    s += __shfl_xor(s, 16, 64); sq += __shfl_xor(sq, 16, 64);
    s += __shfl_xor(s, 32, 64); sq += __shfl_xor(sq, 32, 64);
    const float mean = s * (1.f / 768.f);
    const float rstd = rsqrtf(sq * (1.f / 768.f) - mean * mean + 1e-6f);
    const float mur = mean * rstd;
    // redistribute stats to output-row owners: D row (in 16-tile) = l4*4+rr
    float rstd_r[4], mur_r[4];
#pragma unroll
    for (int rr = 0; rr < 4; ++rr) {
        rstd_r[rr] = __shfl(rstd, l4 * 4 + rr, 64);
        mur_r[rr]  = __shfl(mur,  l4 * 4 + rr, 64);
    }

    const int orow0 = blockIdx.x * 128 + wave * 16 + l4 * 4;
    const int batch = blockIdx.x >> 5;     // 32 blocks per image
#pragma unroll
    for (int f = 0; f < 6; ++f) {
        const int col = f * 16 + l15;
        const float swc = swcb[col];
        const float cbc = swcb[96 + col];
        float colsum = 0.f;
#pragma unroll
        for (int rr = 0; rr < 4; ++rr) {
            const float val = acc[f][rr] * rstd_r[rr] - mur_r[rr] * swc + cbc;
            outb[(size_t)(orow0 + rr) * MID_ + col] = (__bf16)val;
            colsum += val;
        }
        if (part) {
            colsum += __shfl_xor(colsum, 16, 64);
            colsum += __shfl_xor(colsum, 32, 64);
            if (l4 == 0) atomicAdd(&part[batch * MID_ + col], colsum);
        }
    }
}

// ---------------------------------------------------------------------------
// K_mlp: gvec mean from part, MLP (96->24 relu ->4), softmax -> wts [8,4]
// ---------------------------------------------------------------------------
__global__ __launch_bounds__(128) void k_mlp(const float* __restrict__ part,
        const float* __restrict__ m1w, const float* __restrict__ m1b,
        const float* __restrict__ m2w, const float* __restrict__ m2b,
        float* __restrict__ wts) {
    const int b = blockIdx.x, t = threadIdx.x;
    __shared__ float gv[96];
    __shared__ float hid[24];
    __shared__ float lg[4];
    if (t < 96) gv[t] = part[b * MID_ + t] * (1.f / 4096.f);
    __syncthreads();
    if (t < 24) {
        float s = m1b[t];
        for (int c = 0; c < 96; ++c) s += gv[c] * m1w[t * 96 + c];
        hid[t] = fmaxf(s, 0.f);
    }
    __syncthreads();
    if (t < 4) {
        float s = m2b[t];
        for (int j = 0; j < 24; ++j) s += hid[j] * m2w[t * 24 + j];
        lg[t] = s;
    }
    __syncthreads();
    if (t < 4) {
        const float m = fmaxf(fmaxf(lg[0], lg[1]), fmaxf(lg[2], lg[3]));
        const float e = __expf(lg[t] - m);
        const float sum = __expf(lg[0] - m) + __expf(lg[1] - m) +
                          __expf(lg[2] - m) + __expf(lg[3] - m);
        wts[b * 4 + t] = e / sum;
    }
}

// ---------------------------------------------------------------------------
// K_dwconv: depthwise 3x3 conv (zero pad) + SiLU. temb bf16 -> y bf16.
// ---------------------------------------------------------------------------
__global__ __launch_bounds__(256) void k_dwconv(const __bf16* __restrict__ temb,
        const float* __restrict__ dww, const float* __restrict__ dwb,
        __bf16* __restrict__ y) {
    __shared__ float wls[96 * 9];
    __shared__ float bls[96];
    const int t = threadIdx.x;
    for (int i = t; i < 96 * 9; i += 256) wls[i] = dww[i];
    if (t < 96) bls[t] = dwb[t];
    __syncthreads();
    const int b = blockIdx.x >> 6, h = blockIdx.x & 63;
    const __bf16* base = temb + (size_t)b * 4096 * MID_;
    for (int o = t; o < 64 * 96; o += 256) {
        const int w = o / 96;
        const int c = o - w * 96;
        float acc = bls[c];
#pragma unroll
        for (int dh = 0; dh < 3; ++dh) {
            const int hh = h + dh - 1;
            if (hh < 0 || hh > 63) continue;
#pragma unroll
            for (int dw = 0; dw < 3; ++dw) {
                const int ww = w + dw - 1;
                if (ww < 0 || ww > 63) continue;
                acc += (float)base[((size_t)hh * 64 + ww) * MID_ + c] *
                       wls[c * 9 + dh * 3 + dw];
            }
        }
        y[((size_t)(b * 64 + h) * 64 + w) * MID_ + c] =
            (__bf16)(acc / (1.f + __expf(-acc)));
    }
}

// ---------------------------------------------------------------------------
// K_style: style GEMM (y @ pw_w^T + pw_b) fused with modulation:
// common = x_emb * (1 + gamma) + beta -> bf16. K=96 fully staged, 1 barrier.
// ---------------------------------------------------------------------------
__global__ __launch_bounds__(256) void k_style(const __bf16* __restrict__ y,
        const __bf16* __restrict__ wpw, const float* __restrict__ pwb,
        const __bf16* __restrict__ xemb, __bf16* __restrict__ common) {
    __shared__ bf16x8 As[64][13];
    __shared__ bf16x8 Bs[192][13];
    const int t = threadIdx.x;
    const int row0 = blockIdx.x * 64;
    for (int idx = t; idx < 768; idx += 256) {
        const int rr = idx / 12, q = idx - rr * 12;
        As[rr][q] = *reinterpret_cast<const bf16x8*>(
            y + (size_t)(row0 + rr) * MID_ + q * 8);
    }
    for (int idx = t; idx < 2304; idx += 256) {
        const int rr = idx / 12, q = idx - rr * 12;
        Bs[rr][q] = *reinterpret_cast<const bf16x8*>(
            wpw + (size_t)rr * MID_ + q * 8);
    }
    __syncthreads();
    const int lane = t & 63, wave = t >> 6;
    const int l15 = lane & 15, l4 = lane >> 4;
    f32x4 acc[12] = {};
    const int ar = wave * 16 + l15;
#pragma unroll
    for (int kt = 0; kt < 3; ++kt) {
        bf16x8 a = As[ar][kt * 4 + l4];
#pragma unroll
        for (int f = 0; f < 12; ++f) {
            bf16x8 b = Bs[f * 16 + l15][kt * 4 + l4];
            acc[f] = __builtin_amdgcn_mfma_f32_16x16x32_bf16(a, b, acc[f], 0, 0, 0);
        }
    }
    const int orow = row0 + wave * 16 + l4 * 4;
#pragma unroll
    for (int f = 0; f < 6; ++f) {
        const int col = f * 16 + l15;
        const float pbg = pwb[col];
        const float pbb = pwb[col + 96];
#pragma unroll
        for (int rr = 0; rr < 4; ++rr) {
            const float g = acc[f][rr] + pbg;
            const float bt = acc[f + 6][rr] + pbb;
            const float xe = (float)xemb[(size_t)(orow + rr) * MID_ + col];
            common[(size_t)(orow + rr) * MID_ + col] = (__bf16)(xe * (1.f + g) + bt);
        }
    }
}

// ---------------------------------------------------------------------------
// K_circ: circular 7x7 conv (== rfft2/irfft2 product). dyn built in LDS.
// ---------------------------------------------------------------------------
__global__ __launch_bounds__(192) void k_circ(const __bf16* __restrict__ common,
        const float* __restrict__ wts, const float* __restrict__ basis,
        __bf16* __restrict__ outc) {
    __shared__ float dyn[49][96];
    const int t = threadIdx.x;
    const int b = blockIdx.x >> 7;
    const int h = (blockIdx.x >> 1) & 63;
    const int wslice = blockIdx.x & 1;
    const float w0 = wts[b * 4 + 0], w1 = wts[b * 4 + 1];
    const float w2 = wts[b * 4 + 2], w3 = wts[b * 4 + 3];
    for (int idx = t; idx < 4704; idx += 192) {
        const int c = idx / 49;
        const int pq = idx - c * 49;
        const size_t off = (size_t)c * 49 + pq;
        dyn[pq][c] = w0 * basis[off] + w1 * basis[off + 4704] +
                     w2 * basis[off + 9408] + w3 * basis[off + 14112];
    }
    __syncthreads();
    const int c = t % 96;
    const int wg = t / 96;
    const int wbase = wslice * 32 + wg * 16;
    const __bf16* cb = common + (size_t)b * 4096 * MID_ + c;
    float acc[16] = {};
#pragma unroll 1
    for (int p = 0; p < 7; ++p) {
        const int hh = (h + 3 - p) & 63;
        const __bf16* rp = cb + (size_t)hh * 64 * MID_;
        float dynr[7];
#pragma unroll
        for (int q = 0; q < 7; ++q) dynr[q] = dyn[p * 7 + q][c];
#pragma unroll
        for (int i = 0; i < 22; ++i) {
            const int ww = (wbase - 3 + i) & 63;
            const float cm = (float)rp[(size_t)ww * MID_];
#pragma unroll
            for (int q = 0; q < 7; ++q) {
                const int li = i + q - 6;
                if (li >= 0 && li < 16) acc[li] += dynr[q] * cm;
            }
        }
    }
    const size_t obase = ((size_t)(b * 64 + h) * 64 + wbase) * MID_ + c;
#pragma unroll
    for (int li = 0; li < 16; ++li)
        outc[obase + (size_t)li * MID_] = (__bf16)acc[li];
}

// ---------------------------------------------------------------------------
// K_up: out = a_in[32768,96] @ up_w_bf16[768,96]^T + up_b + x  (fp32 out)
// ---------------------------------------------------------------------------
__global__ __launch_bounds__(256) void k_up(const __bf16* __restrict__ a_in,
        const __bf16* __restrict__ wbf, const float* __restrict__ upb,
        const float* __restrict__ x, float* __restrict__ out) {
    __shared__ bf16x8 As[128][13];
    __shared__ bf16x8 Ws[96][13];
    const int t = threadIdx.x;
    const int mt = blockIdx.x >> 3, nt = blockIdx.x & 7;
    const int row0 = mt * 128, col0 = nt * 96;
    for (int idx = t; idx < 1536; idx += 256) {
        const int rr = idx / 12, q = idx - rr * 12;
        As[rr][q] = *reinterpret_cast<const bf16x8*>(
            a_in + (size_t)(row0 + rr) * MID_ + q * 8);
    }
    for (int idx = t; idx < 1152; idx += 256) {
        const int rr = idx / 12, q = idx - rr * 12;
        Ws[rr][q] = *reinterpret_cast<const bf16x8*>(
            wbf + (size_t)(col0 + rr) * MID_ + q * 8);
    }
    __syncthreads();
    const int lane = t & 63, wave = t >> 6;
    const int l15 = lane & 15, l4 = lane >> 4;
    f32x4 acc[2][6] = {};
#pragma unroll
    for (int kt = 0; kt < 3; ++kt) {
        bf16x8 a0 = As[wave * 32 + l15][kt * 4 + l4];
        bf16x8 a1 = As[wave * 32 + 16 + l15][kt * 4 + l4];
#pragma unroll
        for (int f = 0; f < 6; ++f) {
            bf16x8 b = Ws[f * 16 + l15][kt * 4 + l4];
            acc[0][f] = __builtin_amdgcn_mfma_f32_16x16x32_bf16(a0, b, acc[0][f], 0, 0, 0);
            acc[1][f] = __builtin_amdgcn_mfma_f32_16x16x32_bf16(a1, b, acc[1][f], 0, 0, 0);
        }
    }
#pragma unroll
    for (int mr = 0; mr < 2; ++mr) {
        const int orow = row0 + wave * 32 + mr * 16 + l4 * 4;
#pragma unroll
        for (int f = 0; f < 6; ++f) {
            const int col = col0 + f * 16 + l15;
            const float ub = upb[col];
#pragma unroll
            for (int rr = 0; rr < 4; ++rr) {
                const size_t idx = (size_t)(orow + rr) * DIM_ + col;
                out[idx] = acc[mr][f][rr] + ub + x[idx];
            }
        }
    }
}

// ---------------------------------------------------------------------------
extern "C" void kernel_launch(void* const* d_in, const int* in_sizes, int n_in,
                              void* d_out, int out_size, void* d_ws, size_t ws_size,
                              hipStream_t stream) {
    (void)in_sizes; (void)n_in; (void)out_size; (void)ws_size;
    const float* x      = (const float*)d_in[0];
    const float* tt     = (const float*)d_in[1];
    const float* ln_w   = (const float*)d_in[2];
    const float* ln_b   = (const float*)d_in[3];
    const float* down_w = (const float*)d_in[4];
    const float* down_b = (const float*)d_in[5];
    const float* ln1_w  = (const float*)d_in[6];
    const float* ln1_b  = (const float*)d_in[7];
    const float* down1_w= (const float*)d_in[8];
    const float* down1_b= (const float*)d_in[9];
    const float* dw_w   = (const float*)d_in[10];
    const float* dw_b   = (const float*)d_in[11];
    const float* pw_w   = (const float*)d_in[12];
    const float* pw_b   = (const float*)d_in[13];
    const float* m1w    = (const float*)d_in[14];
    const float* m1b    = (const float*)d_in[15];
    const float* m2w    = (const float*)d_in[16];
    const float* m2b    = (const float*)d_in[17];
    const float* basis  = (const float*)d_in[18];
    const float* up_w   = (const float*)d_in[19];
    const float* up_b   = (const float*)d_in[20];
    float* out = (float*)d_out;
    char* ws = (char*)d_ws;

    // workspace layout (bytes)
    __bf16* wln_down  = (__bf16*)(ws + 0);          // 96*768*2  = 147456
    __bf16* wln_down1 = (__bf16*)(ws + 147456);
    __bf16* wbf_up    = (__bf16*)(ws + 294912);     // 768*96*2
    __bf16* wbf_pw    = (__bf16*)(ws + 442368);     // 192*96*2 = 36864
    float*  part      = (float*)(ws + 479232);      // 8*96*4 = 3072
    float*  wts       = (float*)(ws + 482304);      // 32*4
    float*  swcb      = (float*)(ws + 482560);      // 2*192*4 = 1536
    __bf16* x_emb     = (__bf16*)(ws + 524288);     // 32768*96*2 = 6291456
    __bf16* t_emb     = (__bf16*)(ws + 6815744);
    __bf16* ybuf      = (__bf16*)(ws + 13107200);
    __bf16* common    = (__bf16*)(ws + 19398656);
    __bf16* convout   = (__bf16*)(ws + 25690112);

    // opt-in to >64KB dynamic LDS for k_downf (not a stream op; capture-safe)
    (void)hipFuncSetAttribute((const void*)k_downf,
                              hipFuncAttributeMaxDynamicSharedMemorySize, 147456);

    k_wprep<<<93, 256, 0, stream>>>(up_w, pw_w, wbf_up, wbf_pw, part);
    k_wfold<<<48, 256, 0, stream>>>(down_w, down_b, ln_w, ln_b,
                                    down1_w, down1_b, ln1_w, ln1_b,
                                    wln_down, wln_down1, swcb);
    k_downf<<<256, 512, 147456, stream>>>(x, wln_down, swcb, x_emb, part);
    k_downf<<<256, 512, 147456, stream>>>(tt, wln_down1, swcb + 192, t_emb, nullptr);
    k_mlp<<<8, 128, 0, stream>>>(part, m1w, m1b, m2w, m2b, wts);
    k_dwconv<<<512, 256, 0, stream>>>(t_emb, dw_w, dw_b, ybuf);
    k_style<<<512, 256, 0, stream>>>(ybuf, wbf_pw, pw_b, x_emb, common);
    k_circ<<<1024, 192, 0, stream>>>(common, wts, basis, convout);
    k_up<<<2048, 256, 0, stream>>>(convout, wbf_up, up_b, x, out);
}